// Round 4
// baseline (2055.338 us; speedup 1.0000x reference)
//
#include <hip/hip_runtime.h>
#include <hip/hip_bf16.h>

// THLSTM cell fused, MI355X gfx950 — round 4.
// 64 KB LDS (bf16 [h|x] tile + fp8 s-tile) -> 2 WGs/CU (4 waves/SIMD).
// Gate GEMMs = bf16 K=384 part + fp8 K=256 part (mfma 32x32x16).
// Depth-4 B prefetch / depth-2 A prefetch, fully static rotation.

constexpr int Btot = 65536;
constexpr int H    = 256;
constexpr int I    = 128;
constexpr int K1   = 384;   // [h|x]
constexpr int BT   = 64;    // batch rows per WG
constexpr int NTHR = 512;   // 8 waves
constexpr int HXREG = 24576;   // h|x region stride: 48 k8 x 32 rows x 16B
constexpr int SBASE = 49152;   // s-tile base (after 2 hx regions)
constexpr int SREG  = 8192;    // s region stride: 32 k8 x 32 rows x 8B

typedef __bf16 bf16x8  __attribute__((ext_vector_type(8)));
typedef float  f32x16  __attribute__((ext_vector_type(16)));
typedef unsigned short ushort8 __attribute__((ext_vector_type(8)));

__device__ __forceinline__ unsigned short f2bf(float f) {
    unsigned u = __builtin_bit_cast(unsigned, f);
    u += 0x7fffu + ((u >> 16) & 1u);   // RNE
    return (unsigned short)(u >> 16);
}
__device__ __forceinline__ float bf2f(unsigned short s) {
    return __builtin_bit_cast(float, ((unsigned)s) << 16);
}
__device__ __forceinline__ float sigm(float x) {
    return __builtin_amdgcn_rcpf(1.0f + exp2f(-1.4426950408889634f * x));
}
__device__ __forceinline__ float tanh_f(float x) {
    return 1.0f - 2.0f * __builtin_amdgcn_rcpf(1.0f + exp2f(2.8853900817779268f * x));
}

// w0:  [k8(48)][col(256)][8] bf16  (gate s, K=384 over [h|x])
// wgb: 5 x [k8(48)][col(256)][8] bf16  (gates f,i,T,u,o, K=384 part)
// wsf: 5 x [k8(32)][col(256)][8] fp8   (gates f,i,T,u,o, K=256 s part)
__global__ void convert_w(const float* __restrict__ Wh, const float* __restrict__ Wx,
                          const float* __restrict__ Ws, unsigned short* __restrict__ w0,
                          unsigned short* __restrict__ wgb, unsigned char* __restrict__ wsf) {
    const int t  = blockIdx.x * blockDim.x + threadIdx.x;
    const int N0 = 48 * 2048;          // 98304
    const int N1 = 5 * 48 * 2048;      // 491520
    const int N2 = 5 * 32 * 2048;      // 327680
    if (t < N0) {
        const int k8 = t >> 11, rem = t & 2047;
        const int col = rem >> 3, e = rem & 7;
        const int k = k8 * 8 + e;
        const float v = (k < H) ? Wh[col * H + k] : Wx[col * I + (k - H)];
        w0[t] = f2bf(v);
    } else if (t < N0 + N1) {
        const int u   = t - N0;
        const int g1  = u / 98304;
        const int rem = u - g1 * 98304;
        const int k8  = rem >> 11;
        const int col = (rem & 2047) >> 3, e = rem & 7;
        const int k   = k8 * 8 + e;
        const int g   = g1 + 1;
        const float v = (k < H) ? Wh[g * H * H + col * H + k]
                                : Wx[g * H * I + col * I + (k - H)];
        wgb[u] = f2bf(v);
    } else if (t < N0 + N1 + N2) {
        const int u   = t - N0 - N1;
        const int g1  = u >> 16;             // / 65536
        const int rem = u & 65535;
        const int k8  = rem >> 11;
        const int col = (rem & 2047) >> 3, e = rem & 7;
        const int ks  = k8 * 8 + e;
        const float v = Ws[g1 * H * H + col * H + ks];
        const int p = __builtin_amdgcn_cvt_pk_fp8_f32(v, v, 0, false);
        wsf[u] = (unsigned char)(p & 0xff);
    }
}

// bf16 part: NIT iters of K=16, B stride 4096 shorts, A stride 1024 B.
template<int NIT>
__device__ __forceinline__ void gemm_bf16(const unsigned char* Ab, int abase,
        const unsigned short* __restrict__ Wp, f32x16& acc0, f32x16& acc1) {
    bf16x8 bpf[4], a0pf[2], a1pf[2];
    #pragma unroll
    for (int i = 0; i < 4; ++i) bpf[i] = *(const bf16x8*)(Wp + i * 4096);
    #pragma unroll
    for (int i = 0; i < 2; ++i) {
        a0pf[i] = *(const bf16x8*)(Ab + abase + i * 1024);
        a1pf[i] = *(const bf16x8*)(Ab + HXREG + abase + i * 1024);
    }
    #pragma unroll
    for (int i = 0; i < NIT; ++i) {
        const bf16x8 a0 = a0pf[i & 1], a1 = a1pf[i & 1], b = bpf[i & 3];
        if (i + 2 < NIT) {
            a0pf[i & 1] = *(const bf16x8*)(Ab + abase + (i + 2) * 1024);
            a1pf[i & 1] = *(const bf16x8*)(Ab + HXREG + abase + (i + 2) * 1024);
        }
        if (i + 4 < NIT) bpf[i & 3] = *(const bf16x8*)(Wp + (i + 4) * 4096);
        acc0 = __builtin_amdgcn_mfma_f32_32x32x16_bf16(a0, b, acc0, 0, 0, 0);
        acc1 = __builtin_amdgcn_mfma_f32_32x32x16_bf16(a1, b, acc1, 0, 0, 0);
    }
}

// fp8 part: 16 iters of K=16 over s (K=256), B stride 4096 B, A stride 512 B.
__device__ __forceinline__ void gemm_fp8(const unsigned char* Ab, int sA,
        const unsigned char* __restrict__ Wp, f32x16& acc0, f32x16& acc1) {
    long long bpf[4], a0pf[2], a1pf[2];
    #pragma unroll
    for (int i = 0; i < 4; ++i) bpf[i] = *(const long long*)(Wp + i * 4096);
    #pragma unroll
    for (int i = 0; i < 2; ++i) {
        a0pf[i] = *(const long long*)(Ab + sA + i * 512);
        a1pf[i] = *(const long long*)(Ab + SREG + sA + i * 512);
    }
    #pragma unroll
    for (int i = 0; i < 16; ++i) {
        const long long a0 = a0pf[i & 1], a1 = a1pf[i & 1], b = bpf[i & 3];
        if (i + 2 < 16) {
            a0pf[i & 1] = *(const long long*)(Ab + sA + (i + 2) * 512);
            a1pf[i & 1] = *(const long long*)(Ab + SREG + sA + (i + 2) * 512);
        }
        if (i + 4 < 16) bpf[i & 3] = *(const long long*)(Wp + (i + 4) * 4096);
        acc0 = __builtin_amdgcn_mfma_f32_32x32x16_fp8_fp8(a0, b, acc0, 0, 0, 0);
        acc1 = __builtin_amdgcn_mfma_f32_32x32x16_fp8_fp8(a1, b, acc1, 0, 0, 0);
    }
}

__global__ __launch_bounds__(NTHR, 4) void thlstm_fused(
        const float* __restrict__ x_t, const float* __restrict__ delta_t,
        const float* __restrict__ h_prev, const float* __restrict__ c_prev,
        const float* __restrict__ Wst, const float* __restrict__ bias,
        const unsigned short* __restrict__ w0, const unsigned short* __restrict__ wgb,
        const unsigned char* __restrict__ wsf, float* __restrict__ out) {
    __shared__ __align__(16) unsigned char Abuf[65536];   // 64 KB exactly
    const int tid = threadIdx.x;
    const int b0  = blockIdx.x * BT;

    // ---- stage h|x as bf16, fragment order ----
    #pragma unroll
    for (int it = 0; it < 6; ++it) {
        const int c   = it * NTHR + tid;
        const int k8  = c >> 6, row = c & 63;
        const float* src = (k8 < 32) ? (h_prev + (size_t)(b0 + row) * H + k8 * 8)
                                     : (x_t    + (size_t)(b0 + row) * I + (k8 - 32) * 8);
        const float4 v0 = ((const float4*)src)[0];
        const float4 v1 = ((const float4*)src)[1];
        ushort8 p;
        p[0] = f2bf(v0.x); p[1] = f2bf(v0.y); p[2] = f2bf(v0.z); p[3] = f2bf(v0.w);
        p[4] = f2bf(v1.x); p[5] = f2bf(v1.y); p[6] = f2bf(v1.z); p[7] = f2bf(v1.w);
        *(ushort8*)(Abuf + (row >> 5) * HXREG + (k8 * 32 + (row & 31)) * 16) = p;
    }
    __syncthreads();

    const int lane  = tid & 63;
    const int wv    = tid >> 6;
    const int half  = lane >> 5;
    const int l31   = lane & 31;
    const int ocol  = wv * 32 + l31;
    const int rbase = 4 * half;
    const int abase = lane * 16;
    const int wlo   = (half * 256 + ocol) * 8;        // shorts, bf16 B
    const int wf8o  = (half * 256 + ocol) * 8;        // bytes, fp8 B
    const int sA    = SBASE + half * 256 + l31 * 8;   // fp8 A base (region 0)
    const int sEl   = SBASE + ((ocol >> 3) * 32) * 8 + (ocol & 7);  // s elem col-part

    // ---- gate s: K=384 bf16 ----
    {
        f32x16 acc0, acc1;
        #pragma unroll
        for (int r = 0; r < 16; ++r) { acc0[r] = 0.f; acc1[r] = 0.f; }
        gemm_bf16<24>(Abuf, abase, w0 + wlo, acc0, acc1);
        const float wst = Wst[ocol];
        const float bs  = bias[ocol];
        #pragma unroll
        for (int t = 0; t < 2; ++t)
            #pragma unroll
            for (int r = 0; r < 16; ++r) {
                const int mrow = (r & 3) + 8 * (r >> 2) + rbase;
                const float av = t ? acc1[r] : acc0[r];
                const float sv = tanh_f(av + delta_t[b0 + t * 32 + mrow] * wst + bs);
                const int p = __builtin_amdgcn_cvt_pk_fp8_f32(sv, sv, 0, false);
                Abuf[sEl + t * SREG + mrow * 8] = (unsigned char)(p & 0xff);
            }
    }
    __syncthreads();

    float    cacc[2][16];
    unsigned ipk[2][8];

    // ---- gate f (idx 0, bias 1): c = f * c_prev ----
    {
        f32x16 ac0, ac1;
        #pragma unroll
        for (int r = 0; r < 16; ++r) { ac0[r] = 0.f; ac1[r] = 0.f; }
        gemm_bf16<24>(Abuf, abase, wgb + 0 * 98304 + wlo, ac0, ac1);
        gemm_fp8(Abuf, sA, wsf + 0 * 65536 + wf8o, ac0, ac1);
        const float bg = bias[1 * H + ocol];
        #pragma unroll
        for (int t = 0; t < 2; ++t)
            #pragma unroll
            for (int r = 0; r < 16; ++r) {
                const int mrow = (r & 3) + 8 * (r >> 2) + rbase;
                const size_t idx = (size_t)(b0 + t * 32 + mrow) * H + ocol;
                cacc[t][r] = sigm((t ? ac1[r] : ac0[r]) + bg) * c_prev[idx];
            }
    }
    // ---- gate T (idx 2, bias 3): c += T * s (s from LDS fp8) ----
    {
        f32x16 ac0, ac1;
        #pragma unroll
        for (int r = 0; r < 16; ++r) { ac0[r] = 0.f; ac1[r] = 0.f; }
        gemm_bf16<24>(Abuf, abase, wgb + 2 * 98304 + wlo, ac0, ac1);
        gemm_fp8(Abuf, sA, wsf + 2 * 65536 + wf8o, ac0, ac1);
        const float bg = bias[3 * H + ocol];
        #pragma unroll
        for (int t = 0; t < 2; ++t)
            #pragma unroll
            for (int r = 0; r < 16; ++r) {
                const int mrow = (r & 3) + 8 * (r >> 2) + rbase;
                const unsigned sb = Abuf[sEl + t * SREG + mrow * 8];
                const float sv = __builtin_amdgcn_cvt_f32_fp8(sb, 0);
                cacc[t][r] += sigm((t ? ac1[r] : ac0[r]) + bg) * sv;
            }
    }
    // ---- gate i (idx 1, bias 2): packed bf16 ----
    {
        f32x16 ac0, ac1;
        #pragma unroll
        for (int r = 0; r < 16; ++r) { ac0[r] = 0.f; ac1[r] = 0.f; }
        gemm_bf16<24>(Abuf, abase, wgb + 1 * 98304 + wlo, ac0, ac1);
        gemm_fp8(Abuf, sA, wsf + 1 * 65536 + wf8o, ac0, ac1);
        const float bg = bias[2 * H + ocol];
        #pragma unroll
        for (int t = 0; t < 2; ++t) {
            float tmpf = 0.f;
            #pragma unroll
            for (int r = 0; r < 16; ++r) {
                const float sg = sigm((t ? ac1[r] : ac0[r]) + bg);
                if ((r & 1) == 0) tmpf = sg;
                else ipk[t][r >> 1] = (unsigned)f2bf(tmpf) | ((unsigned)f2bf(sg) << 16);
            }
        }
    }
    // ---- gate u (idx 3, bias 4): c += i * tanh(u) ----
    {
        f32x16 ac0, ac1;
        #pragma unroll
        for (int r = 0; r < 16; ++r) { ac0[r] = 0.f; ac1[r] = 0.f; }
        gemm_bf16<24>(Abuf, abase, wgb + 3 * 98304 + wlo, ac0, ac1);
        gemm_fp8(Abuf, sA, wsf + 3 * 65536 + wf8o, ac0, ac1);
        const float bg = bias[4 * H + ocol];
        #pragma unroll
        for (int t = 0; t < 2; ++t)
            #pragma unroll
            for (int r = 0; r < 16; ++r) {
                const float iv = bf2f((unsigned short)((ipk[t][r >> 1] >> ((r & 1) * 16)) & 0xffffu));
                cacc[t][r] += iv * tanh_f((t ? ac1[r] : ac0[r]) + bg);
            }
    }
    // ---- gate o (idx 4, bias 5): outputs ----
    {
        f32x16 ac0, ac1;
        #pragma unroll
        for (int r = 0; r < 16; ++r) { ac0[r] = 0.f; ac1[r] = 0.f; }
        gemm_bf16<24>(Abuf, abase, wgb + 4 * 98304 + wlo, ac0, ac1);
        gemm_fp8(Abuf, sA, wsf + 4 * 65536 + wf8o, ac0, ac1);
        const float bg = bias[5 * H + ocol];
        #pragma unroll
        for (int t = 0; t < 2; ++t)
            #pragma unroll
            for (int r = 0; r < 16; ++r) {
                const int mrow = (r & 3) + 8 * (r >> 2) + rbase;
                const size_t idx = (size_t)(b0 + t * 32 + mrow) * H + ocol;
                const float c = cacc[t][r];
                out[idx] = sigm((t ? ac1[r] : ac0[r]) + bg) * tanh_f(c);
                out[(size_t)Btot * H + idx] = c;
            }
    }
}

extern "C" void kernel_launch(void* const* d_in, const int* in_sizes, int n_in,
                              void* d_out, int out_size, void* d_ws, size_t ws_size,
                              hipStream_t stream) {
    (void)in_sizes; (void)n_in; (void)out_size; (void)ws_size;
    const float* x_t    = (const float*)d_in[0];
    const float* delta  = (const float*)d_in[1];
    const float* h_prev = (const float*)d_in[2];
    const float* c_prev = (const float*)d_in[3];
    const float* Wh     = (const float*)d_in[4];
    const float* Wx     = (const float*)d_in[5];
    const float* Ws     = (const float*)d_in[6];
    const float* Wst    = (const float*)d_in[7];
    const float* bias   = (const float*)d_in[8];
    float* out = (float*)d_out;

    unsigned short* w0  = (unsigned short*)d_ws;       // 98304 bf16
    unsigned short* wgb = w0 + 98304;                  // 491520 bf16
    unsigned char*  wsf = (unsigned char*)(wgb + 491520);  // 327680 fp8

    const int total = 98304 + 491520 + 327680;         // 917504
    convert_w<<<(total + 255) / 256, 256, 0, stream>>>(Wh, Wx, Ws, w0, wgb, wsf);
    thlstm_fused<<<Btot / BT, NTHR, 0, stream>>>(x_t, delta, h_prev, c_prev,
                                                 Wst, bias, w0, wgb, wsf, out);
}

// Round 5
// 1836.835 us; speedup vs baseline: 1.1190x; 1.1190x over previous
//
#include <hip/hip_runtime.h>
#include <hip/hip_bf16.h>

// THLSTM cell fused, MI355X gfx950 — round 5.
// BT=32 rows/WG, 256 threads (4 waves), 40 KB LDS (bf16 hx + bf16 s tile)
// -> 3-4 independent WGs/CU (phase desync keeps HBM streaming).
// Wave owns 32 rows x 64 cols (2 col-tiles). 32x32x16 bf16 MFMA.
// B-ring depth 3 per col-tile stream, A-ring depth 2. launch_bounds(256,3).

constexpr int Btot = 65536;
constexpr int H    = 256;
constexpr int I    = 128;
constexpr int BT   = 32;
constexpr int NTHR = 256;
constexpr int SOFF = 24576;   // s-tile base in LDS (after 48 k8 x 32 x 16B)

typedef __bf16 bf16x8  __attribute__((ext_vector_type(8)));
typedef float  f32x16  __attribute__((ext_vector_type(16)));
typedef unsigned short ushort8 __attribute__((ext_vector_type(8)));

__device__ __forceinline__ unsigned short f2bf(float f) {
    unsigned u = __builtin_bit_cast(unsigned, f);
    u += 0x7fffu + ((u >> 16) & 1u);   // RNE
    return (unsigned short)(u >> 16);
}
__device__ __forceinline__ float bf2f(unsigned short s) {
    return __builtin_bit_cast(float, ((unsigned)s) << 16);
}
__device__ __forceinline__ float sigm(float x) {
    return __builtin_amdgcn_rcpf(1.0f + exp2f(-1.4426950408889634f * x));
}
__device__ __forceinline__ float tanh_f(float x) {
    return 1.0f - 2.0f * __builtin_amdgcn_rcpf(1.0f + exp2f(2.8853900817779268f * x));
}

// Weights bf16, layout [k8][col][8]: elem (col, k=k8*8+e) at (k8*256+col)*8+e.
// w0: 48 k8 (gate s, K=384); wgb: 5 x 48 k8 (f,i,T,u,o hx-part);
// wsb: 5 x 32 k8 (f,i,T,u,o s-part, K=256).
__global__ void convert_w(const float* __restrict__ Wh, const float* __restrict__ Wx,
                          const float* __restrict__ Ws, unsigned short* __restrict__ w0,
                          unsigned short* __restrict__ wgb, unsigned short* __restrict__ wsb) {
    const int t  = blockIdx.x * blockDim.x + threadIdx.x;
    const int N0 = 48 * 2048;          // 98304
    const int N1 = 5 * 48 * 2048;      // 491520
    const int N2 = 5 * 32 * 2048;      // 327680
    if (t < N0) {
        const int k8 = t >> 11, rem = t & 2047;
        const int col = rem >> 3, e = rem & 7;
        const int k = k8 * 8 + e;
        const float v = (k < H) ? Wh[col * H + k] : Wx[col * I + (k - H)];
        w0[t] = f2bf(v);
    } else if (t < N0 + N1) {
        const int u   = t - N0;
        const int g1  = u / 98304;
        const int rem = u - g1 * 98304;
        const int k8  = rem >> 11;
        const int col = (rem & 2047) >> 3, e = rem & 7;
        const int k   = k8 * 8 + e;
        const int g   = g1 + 1;
        const float v = (k < H) ? Wh[g * H * H + col * H + k]
                                : Wx[g * H * I + col * I + (k - H)];
        wgb[u] = f2bf(v);
    } else if (t < N0 + N1 + N2) {
        const int u   = t - N0 - N1;
        const int g1  = u >> 16;
        const int rem = u & 65535;
        const int k8  = rem >> 11;
        const int col = (rem & 2047) >> 3, e = rem & 7;
        wsb[u] = f2bf(Ws[g1 * H * H + col * H + k8 * 8 + e]);
    }
}

// Per iter: 1 A ds_read (shared), 2 B global loads (col-tiles 0/1), 2 MFMA.
// A ring depth 2, B ring depth 3 per stream. Fully static indexing.
template<int NIT>
__device__ __forceinline__ void gemm2(const unsigned char* Ab, int abase,
        const unsigned short* __restrict__ Wp, f32x16& acc0, f32x16& acc1) {
    bf16x8 b0[3], b1[3], a[2];
    #pragma unroll
    for (int i = 0; i < 3; ++i) {
        b0[i] = *(const bf16x8*)(Wp + i * 4096);
        b1[i] = *(const bf16x8*)(Wp + i * 4096 + 256);
    }
    #pragma unroll
    for (int i = 0; i < 2; ++i)
        a[i] = *(const bf16x8*)(Ab + abase + i * 1024);
    #pragma unroll
    for (int i = 0; i < NIT; ++i) {
        const bf16x8 av = a[i & 1], bv0 = b0[i % 3], bv1 = b1[i % 3];
        if (i + 2 < NIT)
            a[i & 1] = *(const bf16x8*)(Ab + abase + (i + 2) * 1024);
        if (i + 3 < NIT) {
            b0[i % 3] = *(const bf16x8*)(Wp + (i + 3) * 4096);
            b1[i % 3] = *(const bf16x8*)(Wp + (i + 3) * 4096 + 256);
        }
        acc0 = __builtin_amdgcn_mfma_f32_32x32x16_bf16(av, bv0, acc0, 0, 0, 0);
        acc1 = __builtin_amdgcn_mfma_f32_32x32x16_bf16(av, bv1, acc1, 0, 0, 0);
    }
}

__global__ __launch_bounds__(NTHR, 3) void thlstm_fused(
        const float* __restrict__ x_t, const float* __restrict__ delta_t,
        const float* __restrict__ h_prev, const float* __restrict__ c_prev,
        const float* __restrict__ Wst, const float* __restrict__ bias,
        const unsigned short* __restrict__ w0, const unsigned short* __restrict__ wgb,
        const unsigned short* __restrict__ wsb, float* __restrict__ out) {
    __shared__ __align__(16) unsigned char Abuf[40960];   // 24 KB hx + 16 KB s
    const int tid = threadIdx.x;
    const int b0  = blockIdx.x * BT;

    // ---- stage h|x bf16 fragment-order: chunk (k8, row) at k8*512 + row*16 ----
    #pragma unroll
    for (int it = 0; it < 6; ++it) {
        const int c   = it * NTHR + tid;
        const int k8  = c >> 5, row = c & 31;
        const float* src = (k8 < 32) ? (h_prev + (size_t)(b0 + row) * H + k8 * 8)
                                     : (x_t    + (size_t)(b0 + row) * I + (k8 - 32) * 8);
        const float4 v0 = ((const float4*)src)[0];
        const float4 v1 = ((const float4*)src)[1];
        ushort8 p;
        p[0] = f2bf(v0.x); p[1] = f2bf(v0.y); p[2] = f2bf(v0.z); p[3] = f2bf(v0.w);
        p[4] = f2bf(v1.x); p[5] = f2bf(v1.y); p[6] = f2bf(v1.z); p[7] = f2bf(v1.w);
        *(ushort8*)(Abuf + k8 * 512 + row * 16) = p;
    }
    __syncthreads();

    const int lane  = tid & 63;
    const int wv    = tid >> 6;          // 0..3
    const int half  = lane >> 5;
    const int l31   = lane & 31;
    const int oc0   = wv * 64 + l31;     // col-tile 0 column; tile 1 = +32
    const int rbase = 4 * half;
    const int abase = lane * 16;
    const int wbase = half * 2048 + oc0 * 8;   // shorts

    unsigned spk[2][8];   // this thread's s values packed bf16 (for T*s term)

    // ---- gate s: K=384 ----
    {
        f32x16 acc0, acc1;
        #pragma unroll
        for (int r = 0; r < 16; ++r) { acc0[r] = 0.f; acc1[r] = 0.f; }
        gemm2<24>(Abuf, abase, w0 + wbase, acc0, acc1);
        #pragma unroll
        for (int t = 0; t < 2; ++t) {
            const int oc = oc0 + t * 32;
            const float wst = Wst[oc];
            const float bs  = bias[oc];
            float prev = 0.f;
            #pragma unroll
            for (int r = 0; r < 16; ++r) {
                const int mrow = (r & 3) + 8 * (r >> 2) + rbase;
                const float av = t ? acc1[r] : acc0[r];
                const float sv = tanh_f(av + delta_t[b0 + mrow] * wst + bs);
                *(unsigned short*)(Abuf + SOFF + (oc >> 3) * 512 + mrow * 16 + (oc & 7) * 2) = f2bf(sv);
                if ((r & 1) == 0) prev = sv;
                else spk[t][r >> 1] = (unsigned)f2bf(prev) | ((unsigned)f2bf(sv) << 16);
            }
        }
    }
    __syncthreads();

    float    cacc[2][16];
    unsigned ipk[2][8];

    // ---- gate f (wgb 0, bias 1): c = f * c_prev ----
    {
        f32x16 ac0, ac1;
        #pragma unroll
        for (int r = 0; r < 16; ++r) { ac0[r] = 0.f; ac1[r] = 0.f; }
        gemm2<24>(Abuf, abase, wgb + 0 * 98304 + wbase, ac0, ac1);
        gemm2<16>(Abuf + SOFF, abase, wsb + 0 * 65536 + wbase, ac0, ac1);
        #pragma unroll
        for (int t = 0; t < 2; ++t) {
            const int oc = oc0 + t * 32;
            const float bg = bias[1 * H + oc];
            #pragma unroll
            for (int r = 0; r < 16; ++r) {
                const int mrow = (r & 3) + 8 * (r >> 2) + rbase;
                const size_t idx = (size_t)(b0 + mrow) * H + oc;
                cacc[t][r] = sigm((t ? ac1[r] : ac0[r]) + bg) * c_prev[idx];
            }
        }
    }
    // ---- gate T (wgb 2, bias 3): c += T * s (s from regs) ----
    {
        f32x16 ac0, ac1;
        #pragma unroll
        for (int r = 0; r < 16; ++r) { ac0[r] = 0.f; ac1[r] = 0.f; }
        gemm2<24>(Abuf, abase, wgb + 2 * 98304 + wbase, ac0, ac1);
        gemm2<16>(Abuf + SOFF, abase, wsb + 2 * 65536 + wbase, ac0, ac1);
        #pragma unroll
        for (int t = 0; t < 2; ++t) {
            const int oc = oc0 + t * 32;
            const float bg = bias[3 * H + oc];
            #pragma unroll
            for (int r = 0; r < 16; ++r) {
                const float sv = bf2f((unsigned short)((spk[t][r >> 1] >> ((r & 1) * 16)) & 0xffffu));
                cacc[t][r] += sigm((t ? ac1[r] : ac0[r]) + bg) * sv;
            }
        }
    }
    // ---- gate i (wgb 1, bias 2): pack sigm(i) ----
    {
        f32x16 ac0, ac1;
        #pragma unroll
        for (int r = 0; r < 16; ++r) { ac0[r] = 0.f; ac1[r] = 0.f; }
        gemm2<24>(Abuf, abase, wgb + 1 * 98304 + wbase, ac0, ac1);
        gemm2<16>(Abuf + SOFF, abase, wsb + 1 * 65536 + wbase, ac0, ac1);
        #pragma unroll
        for (int t = 0; t < 2; ++t) {
            const int oc = oc0 + t * 32;
            const float bg = bias[2 * H + oc];
            float prev = 0.f;
            #pragma unroll
            for (int r = 0; r < 16; ++r) {
                const float sg = sigm((t ? ac1[r] : ac0[r]) + bg);
                if ((r & 1) == 0) prev = sg;
                else ipk[t][r >> 1] = (unsigned)f2bf(prev) | ((unsigned)f2bf(sg) << 16);
            }
        }
    }
    // ---- gate u (wgb 3, bias 4): c += i * tanh(u) ----
    {
        f32x16 ac0, ac1;
        #pragma unroll
        for (int r = 0; r < 16; ++r) { ac0[r] = 0.f; ac1[r] = 0.f; }
        gemm2<24>(Abuf, abase, wgb + 3 * 98304 + wbase, ac0, ac1);
        gemm2<16>(Abuf + SOFF, abase, wsb + 3 * 65536 + wbase, ac0, ac1);
        #pragma unroll
        for (int t = 0; t < 2; ++t) {
            const int oc = oc0 + t * 32;
            const float bg = bias[4 * H + oc];
            #pragma unroll
            for (int r = 0; r < 16; ++r) {
                const float iv = bf2f((unsigned short)((ipk[t][r >> 1] >> ((r & 1) * 16)) & 0xffffu));
                cacc[t][r] += iv * tanh_f((t ? ac1[r] : ac0[r]) + bg);
            }
        }
    }
    // ---- gate o (wgb 4, bias 5): outputs ----
    {
        f32x16 ac0, ac1;
        #pragma unroll
        for (int r = 0; r < 16; ++r) { ac0[r] = 0.f; ac1[r] = 0.f; }
        gemm2<24>(Abuf, abase, wgb + 4 * 98304 + wbase, ac0, ac1);
        gemm2<16>(Abuf + SOFF, abase, wsb + 4 * 65536 + wbase, ac0, ac1);
        #pragma unroll
        for (int t = 0; t < 2; ++t) {
            const int oc = oc0 + t * 32;
            const float bg = bias[5 * H + oc];
            #pragma unroll
            for (int r = 0; r < 16; ++r) {
                const int mrow = (r & 3) + 8 * (r >> 2) + rbase;
                const size_t idx = (size_t)(b0 + mrow) * H + oc;
                const float c = cacc[t][r];
                out[idx] = sigm((t ? ac1[r] : ac0[r]) + bg) * tanh_f(c);
                out[(size_t)Btot * H + idx] = c;
            }
        }
    }
}

extern "C" void kernel_launch(void* const* d_in, const int* in_sizes, int n_in,
                              void* d_out, int out_size, void* d_ws, size_t ws_size,
                              hipStream_t stream) {
    (void)in_sizes; (void)n_in; (void)out_size; (void)ws_size;
    const float* x_t    = (const float*)d_in[0];
    const float* delta  = (const float*)d_in[1];
    const float* h_prev = (const float*)d_in[2];
    const float* c_prev = (const float*)d_in[3];
    const float* Wh     = (const float*)d_in[4];
    const float* Wx     = (const float*)d_in[5];
    const float* Ws     = (const float*)d_in[6];
    const float* Wst    = (const float*)d_in[7];
    const float* bias   = (const float*)d_in[8];
    float* out = (float*)d_out;

    unsigned short* w0  = (unsigned short*)d_ws;   // 98304 bf16
    unsigned short* wgb = w0 + 98304;              // 491520 bf16
    unsigned short* wsb = wgb + 491520;            // 327680 bf16

    const int total = 98304 + 491520 + 327680;     // 917504
    convert_w<<<(total + 255) / 256, 256, 0, stream>>>(Wh, Wx, Ws, w0, wgb, wsb);
    thlstm_fused<<<Btot / BT, NTHR, 0, stream>>>(x_t, delta, h_prev, c_prev,
                                                 Wst, bias, w0, wgb, wsb, out);
}